// Round 1
// baseline (2286.435 us; speedup 1.0000x reference)
//
#include <hip/hip_runtime.h>
#include <cstdint>
#include <cstddef>

// ---------------------------------------------------------------------------
// GCN 3-layer forward: h1 = relu(conv(x,W1,b1)); h2 = relu(conv(h1,W2,b2));
// out = conv(h2,W3,b3).  conv: h = X@W; out[dst] += dinv[src]*dinv[dst]*h[src]
// (edges + self-loops); out += b.  Self-loop term fused into epilogue.
// ---------------------------------------------------------------------------

// Edge index may arrive as int32 or int64 depending on harness conversion.
// Runtime-detected flag (1 = int64, 0 = int32).
__device__ __forceinline__ int eidx_at(const void* p, long long i, int is64) {
  if (is64) return (int)((const long long*)p)[i];
  return ((const int*)p)[i];
}

__global__ void k_flag(const void* eidx, int* flag) {
  // int64 node indices are all < 1e5. If the buffer is really int32 pairs,
  // reading as u64 gives (lo | hi<<32) with hi a random index; hi>=1 with
  // prob 1-1e-5 per word -> value >= 2^32. Scan 256 words.
  const unsigned long long* p = (const unsigned long long*)eidx;
  int is64 = 1;
  for (int i = 0; i < 256; ++i) {
    if (p[i] > 1000000000ULL) { is64 = 0; break; }
  }
  *flag = is64;
}

__global__ void k_deg_init(int* deg, int n) {
  int i = blockIdx.x * blockDim.x + threadIdx.x;
  if (i < n) deg[i] = 1;  // self-loop
}

__global__ void k_deg_edges(const void* eidx, const int* flag, int* deg, int E) {
  int e = blockIdx.x * blockDim.x + threadIdx.x;
  if (e >= E) return;
  int is64 = *flag;
  int d = eidx_at(eidx, (long long)E + e, is64);
  atomicAdd(&deg[d], 1);
}

__global__ void k_dinv(const int* __restrict__ deg, float* __restrict__ dinv, int n) {
  int i = blockIdx.x * blockDim.x + threadIdx.x;
  if (i < n) dinv[i] = rsqrtf((float)deg[i]);
}

// X [n,64] @ W [64,COUT] -> T [n,COUT]. One thread per row, COUT accumulators,
// W staged in LDS (broadcast reads, conflict-free).
template <int COUT>
__global__ __launch_bounds__(256) void k_matmul(const float* __restrict__ X,
                                                const float* __restrict__ W,
                                                float* __restrict__ T, int n) {
  __shared__ float Ws[64 * COUT];
  for (int i = threadIdx.x; i < 64 * COUT; i += blockDim.x) Ws[i] = W[i];
  __syncthreads();
  int r = blockIdx.x * blockDim.x + threadIdx.x;
  if (r >= n) return;
  float acc[COUT];
#pragma unroll
  for (int j = 0; j < COUT; ++j) acc[j] = 0.f;
  const float4* xr = (const float4*)(X + (size_t)r * 64);
#pragma unroll
  for (int k4 = 0; k4 < 16; ++k4) {
    float4 xv = xr[k4];
    const float xs[4] = {xv.x, xv.y, xv.z, xv.w};
#pragma unroll
    for (int c = 0; c < 4; ++c) {
      int k = k4 * 4 + c;
#pragma unroll
      for (int j = 0; j < COUT; ++j) acc[j] += xs[c] * Ws[k * COUT + j];
    }
  }
  float4* tr = (float4*)(T + (size_t)r * COUT);
#pragma unroll
  for (int j4 = 0; j4 < COUT / 4; ++j4)
    tr[j4] = make_float4(acc[4 * j4], acc[4 * j4 + 1], acc[4 * j4 + 2], acc[4 * j4 + 3]);
}

// out[dst] += dinv[src]*dinv[dst] * T[src]   (COUT/4 lanes per edge, float4)
template <int COUT>
__global__ __launch_bounds__(256) void k_scatter(const float* __restrict__ T,
                                                 const void* eidx, const int* flag,
                                                 const float* __restrict__ dinv,
                                                 float* out, int E) {
  const int LPE = COUT / 4;
  long long gid = (long long)blockIdx.x * blockDim.x + threadIdx.x;
  int e = (int)(gid / LPE);
  int l = (int)(gid % LPE);
  if (e >= E) return;
  int is64 = *flag;
  int s = eidx_at(eidx, e, is64);
  int d = eidx_at(eidx, (long long)E + e, is64);
  float nrm = dinv[s] * dinv[d];
  float4 v = ((const float4*)(T + (size_t)s * COUT))[l];
  float* op = out + (size_t)d * COUT + l * 4;
  unsafeAtomicAdd(op + 0, v.x * nrm);
  unsafeAtomicAdd(op + 1, v.y * nrm);
  unsafeAtomicAdd(op + 2, v.z * nrm);
  unsafeAtomicAdd(op + 3, v.w * nrm);
}

// out = maybe_relu(out + dinv^2 * T + b)   (self-loop message + bias + act)
template <int COUT, bool RELU>
__global__ __launch_bounds__(256) void k_finish(float* __restrict__ out,
                                                const float* __restrict__ T,
                                                const float* __restrict__ dinv,
                                                const float* __restrict__ b, int n) {
  const int LPR = COUT / 4;
  long long gid = (long long)blockIdx.x * blockDim.x + threadIdx.x;
  int r = (int)(gid / LPR);
  int l = (int)(gid % LPR);
  if (r >= n) return;
  float di = dinv[r];
  float sl = di * di;
  float4 o = ((const float4*)(out + (size_t)r * COUT))[l];
  float4 t = ((const float4*)(T + (size_t)r * COUT))[l];
  float4 bb = ((const float4*)b)[l];
  float rx = o.x + sl * t.x + bb.x;
  float ry = o.y + sl * t.y + bb.y;
  float rz = o.z + sl * t.z + bb.z;
  float rw = o.w + sl * t.w + bb.w;
  if (RELU) {
    rx = fmaxf(rx, 0.f); ry = fmaxf(ry, 0.f);
    rz = fmaxf(rz, 0.f); rw = fmaxf(rw, 0.f);
  }
  ((float4*)(out + (size_t)r * COUT))[l] = make_float4(rx, ry, rz, rw);
}

extern "C" void kernel_launch(void* const* d_in, const int* in_sizes, int n_in,
                              void* d_out, int out_size, void* d_ws, size_t ws_size,
                              hipStream_t stream) {
  const float* x  = (const float*)d_in[0];
  const void*  ei = d_in[1];
  const float* W1 = (const float*)d_in[2];
  const float* b1 = (const float*)d_in[3];
  const float* W2 = (const float*)d_in[4];
  const float* b2 = (const float*)d_in[5];
  const float* W3 = (const float*)d_in[6];
  const float* b3 = (const float*)d_in[7];
  float* out = (float*)d_out;

  const int n = in_sizes[0] / 64;   // 100000
  const int E = in_sizes[1] / 2;    // 1000000

  // workspace carve-up (256B aligned)
  char* ws = (char*)d_ws;
  size_t off = 0;
  auto carve = [&](size_t bytes) -> void* {
    void* p = ws + off;
    off = (off + bytes + 255) & ~(size_t)255;
    return p;
  };
  int*   flag = (int*)carve(16);
  int*   deg  = (int*)carve(sizeof(int) * n);
  float* dinv = (float*)carve(sizeof(float) * n);
  float* T    = (float*)carve(sizeof(float) * (size_t)n * 64);
  float* A    = (float*)carve(sizeof(float) * (size_t)n * 64);

  const int B = 256;
  const int gN   = (n + B - 1) / B;
  const int gE   = (E + B - 1) / B;

  k_flag<<<1, 1, 0, stream>>>(ei, flag);
  k_deg_init<<<gN, B, 0, stream>>>(deg, n);
  k_deg_edges<<<gE, B, 0, stream>>>(ei, flag, deg, E);
  k_dinv<<<gN, B, 0, stream>>>(deg, dinv, n);

  const int gS64 = (int)(((long long)E * 16 + B - 1) / B);
  const int gS32 = (int)(((long long)E * 8 + B - 1) / B);
  const int gF64 = (int)(((long long)n * 16 + B - 1) / B);
  const int gF32 = (int)(((long long)n * 8 + B - 1) / B);

  // ---- layer 1: x -> A ----
  k_matmul<64><<<gN, B, 0, stream>>>(x, W1, T, n);
  hipMemsetAsync(A, 0, sizeof(float) * (size_t)n * 64, stream);
  k_scatter<64><<<gS64, B, 0, stream>>>(T, ei, flag, dinv, A, E);
  k_finish<64, true><<<gF64, B, 0, stream>>>(A, T, dinv, b1, n);

  // ---- layer 2: A -> A ----
  k_matmul<64><<<gN, B, 0, stream>>>(A, W2, T, n);
  hipMemsetAsync(A, 0, sizeof(float) * (size_t)n * 64, stream);
  k_scatter<64><<<gS64, B, 0, stream>>>(T, ei, flag, dinv, A, E);
  k_finish<64, true><<<gF64, B, 0, stream>>>(A, T, dinv, b2, n);

  // ---- layer 3: A -> out ----
  k_matmul<32><<<gN, B, 0, stream>>>(A, W3, T, n);
  hipMemsetAsync(out, 0, sizeof(float) * (size_t)n * 32, stream);
  k_scatter<32><<<gS32, B, 0, stream>>>(T, ei, flag, dinv, out, E);
  k_finish<32, false><<<gF32, B, 0, stream>>>(out, T, dinv, b3, n);
}

// Round 2
// 617.269 us; speedup vs baseline: 3.7041x; 3.7041x over previous
//
#include <hip/hip_runtime.h>
#include <cstdint>
#include <cstddef>

// ---------------------------------------------------------------------------
// GCN 3-layer forward, CSR-gather formulation (no f32 atomics):
//   build CSR by dst once per call; per layer: T = X@W, then per dst row
//   acc[lane] = sum_j nrm[j]*T[src[j]][lane]  + dinv^2*T[row][lane] + b[lane]
//   (self-loop + bias + relu fused into the gather epilogue).
// ---------------------------------------------------------------------------

__device__ __forceinline__ int eidx_at(const void* p, long long i, int is64) {
  if (is64) return (int)((const long long*)p)[i];
  return ((const int*)p)[i];
}

__global__ void k_flag(const void* eidx, int* flag) {
  // int64 node indices are all < 1e5; int32 data read as u64 has a random
  // index in the high word -> huge values. Scan 256 words.
  const unsigned long long* p = (const unsigned long long*)eidx;
  int is64 = 1;
  for (int i = 0; i < 256; ++i) {
    if (p[i] > 1000000000ULL) { is64 = 0; break; }
  }
  *flag = is64;
}

// histogram of dst (real edges only; self-loop added in dinv)
__global__ void k_count(const void* eidx, const int* flag, int* cnt, int E) {
  int e = blockIdx.x * blockDim.x + threadIdx.x;
  if (e >= E) return;
  int is64 = *flag;
  int d = eidx_at(eidx, (long long)E + e, is64);
  atomicAdd(&cnt[d], 1);
}

__global__ void k_dinv(const int* __restrict__ cnt, float* __restrict__ dinv, int n) {
  int i = blockIdx.x * blockDim.x + threadIdx.x;
  if (i < n) dinv[i] = rsqrtf((float)(cnt[i] + 1));  // +1 self-loop
}

// single-block exclusive scan of cnt[0..n) -> rowptr[0..n], cursor copy
__global__ __launch_bounds__(1024) void k_scan(const int* __restrict__ cnt,
                                               int* __restrict__ rowptr,
                                               int* __restrict__ cursor, int n) {
  const int T = 1024;
  int t = threadIdx.x;
  int C = (n + T - 1) / T;
  int lo = t * C;
  int hi = lo + C; if (hi > n) hi = n; if (lo > n) lo = n;
  int local = 0;
  for (int i = lo; i < hi; ++i) local += cnt[i];
  __shared__ int sh[1024];
  sh[t] = local;
  __syncthreads();
  for (int off = 1; off < T; off <<= 1) {
    int v = (t >= off) ? sh[t - off] : 0;
    __syncthreads();
    sh[t] += v;
    __syncthreads();
  }
  int run = sh[t] - local;  // exclusive offset of this chunk
  for (int i = lo; i < hi; ++i) {
    rowptr[i] = run;
    cursor[i] = run;
    run += cnt[i];
  }
  if (t == T - 1) rowptr[n] = run;
}

__global__ void k_fill(const void* eidx, const int* flag,
                       const float* __restrict__ dinv, int* cursor,
                       int* __restrict__ csr_src, float* __restrict__ csr_nrm, int E) {
  int e = blockIdx.x * blockDim.x + threadIdx.x;
  if (e >= E) return;
  int is64 = *flag;
  int s = eidx_at(eidx, e, is64);
  int d = eidx_at(eidx, (long long)E + e, is64);
  int pos = atomicAdd(&cursor[d], 1);
  csr_src[pos] = s;
  csr_nrm[pos] = dinv[s] * dinv[d];
}

// X [n,64] @ W [64,COUT] -> T [n,COUT]. One thread per row, W in LDS.
template <int COUT>
__global__ __launch_bounds__(256) void k_matmul(const float* __restrict__ X,
                                                const float* __restrict__ W,
                                                float* __restrict__ T, int n) {
  __shared__ float Ws[64 * COUT];
  for (int i = threadIdx.x; i < 64 * COUT; i += blockDim.x) Ws[i] = W[i];
  __syncthreads();
  int r = blockIdx.x * blockDim.x + threadIdx.x;
  if (r >= n) return;
  float acc[COUT];
#pragma unroll
  for (int j = 0; j < COUT; ++j) acc[j] = 0.f;
  const float4* xr = (const float4*)(X + (size_t)r * 64);
#pragma unroll
  for (int k4 = 0; k4 < 16; ++k4) {
    float4 xv = xr[k4];
    const float xs[4] = {xv.x, xv.y, xv.z, xv.w};
#pragma unroll
    for (int c = 0; c < 4; ++c) {
      int k = k4 * 4 + c;
#pragma unroll
      for (int j = 0; j < COUT; ++j) acc[j] += xs[c] * Ws[k * COUT + j];
    }
  }
  float4* tr = (float4*)(T + (size_t)r * COUT);
#pragma unroll
  for (int j4 = 0; j4 < COUT / 4; ++j4)
    tr[j4] = make_float4(acc[4 * j4], acc[4 * j4 + 1], acc[4 * j4 + 2], acc[4 * j4 + 3]);
}

// One wave per dst row: gather+accumulate incoming edges, fuse self-loop,
// bias, relu. lane < COUT lanes carry one output float each.
template <int COUT, bool RELU>
__global__ __launch_bounds__(256) void k_gather(const float* __restrict__ T,
                                                const int* __restrict__ rowptr,
                                                const int* __restrict__ csr_src,
                                                const float* __restrict__ csr_nrm,
                                                const float* __restrict__ dinv,
                                                const float* __restrict__ b,
                                                float* __restrict__ out, int n) {
  int wave = blockIdx.x * (blockDim.x >> 6) + (threadIdx.x >> 6);
  int lane = threadIdx.x & 63;
  int row = __builtin_amdgcn_readfirstlane(wave);
  if (row >= n) return;
  int beg = rowptr[row];
  int end = rowptr[row + 1];
  float dr = dinv[row];
  float acc = 0.f;
  for (int j = beg; j < end; ++j) {
    int s = csr_src[j];        // scalar load (j uniform)
    float nrm = csr_nrm[j];    // scalar load, independent of s
    if (lane < COUT) acc = fmaf(nrm, T[(size_t)s * COUT + lane], acc);
  }
  if (lane < COUT) {
    float v = acc + dr * dr * T[(size_t)row * COUT + lane] + b[lane];
    if (RELU) v = fmaxf(v, 0.f);
    out[(size_t)row * COUT + lane] = v;
  }
}

extern "C" void kernel_launch(void* const* d_in, const int* in_sizes, int n_in,
                              void* d_out, int out_size, void* d_ws, size_t ws_size,
                              hipStream_t stream) {
  const float* x  = (const float*)d_in[0];
  const void*  ei = d_in[1];
  const float* W1 = (const float*)d_in[2];
  const float* b1 = (const float*)d_in[3];
  const float* W2 = (const float*)d_in[4];
  const float* b2 = (const float*)d_in[5];
  const float* W3 = (const float*)d_in[6];
  const float* b3 = (const float*)d_in[7];
  float* out = (float*)d_out;

  const int n = in_sizes[0] / 64;   // 100000
  const int E = in_sizes[1] / 2;    // 1000000

  char* ws = (char*)d_ws;
  size_t off = 0;
  auto carve = [&](size_t bytes) -> void* {
    void* p = ws + off;
    off = (off + bytes + 255) & ~(size_t)255;
    return p;
  };
  int*   flag    = (int*)carve(16);
  int*   cnt     = (int*)carve(sizeof(int) * n);
  float* dinv    = (float*)carve(sizeof(float) * n);
  int*   rowptr  = (int*)carve(sizeof(int) * (n + 1));
  int*   cursor  = (int*)carve(sizeof(int) * n);
  int*   csr_src = (int*)carve(sizeof(int) * E);
  float* csr_nrm = (float*)carve(sizeof(float) * E);
  float* T       = (float*)carve(sizeof(float) * (size_t)n * 64);
  float* A       = (float*)carve(sizeof(float) * (size_t)n * 64);

  const int B = 256;
  const int gN = (n + B - 1) / B;
  const int gE = (E + B - 1) / B;
  const int gW = (n + 3) / 4;  // 4 waves/block, 1 wave/row

  // ---- graph preprocessing (once per call, shared by all 3 layers) ----
  k_flag<<<1, 1, 0, stream>>>(ei, flag);
  hipMemsetAsync(cnt, 0, sizeof(int) * n, stream);
  k_count<<<gE, B, 0, stream>>>(ei, flag, cnt, E);
  k_dinv<<<gN, B, 0, stream>>>(cnt, dinv, n);
  k_scan<<<1, 1024, 0, stream>>>(cnt, rowptr, cursor, n);
  k_fill<<<gE, B, 0, stream>>>(ei, flag, dinv, cursor, csr_src, csr_nrm, E);

  // ---- layer 1: x -> A ----
  k_matmul<64><<<gN, B, 0, stream>>>(x, W1, T, n);
  k_gather<64, true><<<gW, B, 0, stream>>>(T, rowptr, csr_src, csr_nrm, dinv, b1, A, n);

  // ---- layer 2: A -> A ----
  k_matmul<64><<<gN, B, 0, stream>>>(A, W2, T, n);
  k_gather<64, true><<<gW, B, 0, stream>>>(T, rowptr, csr_src, csr_nrm, dinv, b2, A, n);

  // ---- layer 3: A -> out ----
  k_matmul<32><<<gN, B, 0, stream>>>(A, W3, T, n);
  k_gather<32, false><<<gW, B, 0, stream>>>(T, rowptr, csr_src, csr_nrm, dinv, b3, out, n);
}

// Round 3
// 412.158 us; speedup vs baseline: 5.5475x; 1.4977x over previous
//
#include <hip/hip_runtime.h>
#include <cstdint>
#include <cstddef>

// ---------------------------------------------------------------------------
// GCN 3-layer forward, CSR-gather formulation (no f32 atomics):
//   build CSR by dst once per call; per layer: T = X@W, then per dst row
//   acc[lane] = sum_j nrm[j]*T[src[j]][lane]  + dinv^2*T[row][lane] + b[lane]
//   (self-loop + bias + relu fused into the gather epilogue).
// Scan is now a 3-phase device-wide scan (round 2: single-block scan was
// 231 us at 0.15% occupancy).
// ---------------------------------------------------------------------------

__device__ __forceinline__ int eidx_at(const void* p, long long i, int is64) {
  if (is64) return (int)((const long long*)p)[i];
  return ((const int*)p)[i];
}

__global__ void k_flag(const void* eidx, int* flag) {
  const unsigned long long* p = (const unsigned long long*)eidx;
  int is64 = 1;
  for (int i = 0; i < 256; ++i) {
    if (p[i] > 1000000000ULL) { is64 = 0; break; }
  }
  *flag = is64;
}

// histogram of dst (real edges only; self-loop handled in dinv/epilogue)
__global__ void k_count(const void* eidx, const int* flag, int* cnt, int E) {
  int e = blockIdx.x * blockDim.x + threadIdx.x;
  if (e >= E) return;
  int is64 = *flag;
  int d = eidx_at(eidx, (long long)E + e, is64);
  atomicAdd(&cnt[d], 1);
}

__global__ void k_dinv(const int* __restrict__ cnt, float* __restrict__ dinv, int n) {
  int i = blockIdx.x * blockDim.x + threadIdx.x;
  if (i < n) dinv[i] = rsqrtf((float)(cnt[i] + 1));  // +1 self-loop
}

// ---- 3-phase scan: 1024 elems per block (256 thr x 4) ----
__global__ __launch_bounds__(256) void k_scan1(const int* __restrict__ cnt,
                                               int* __restrict__ part, int n) {
  int b = blockIdx.x, t = threadIdx.x;
  int base = b * 1024 + t * 4;
  int s = 0;
#pragma unroll
  for (int i = 0; i < 4; ++i) { int idx = base + i; if (idx < n) s += cnt[idx]; }
  __shared__ int sh[256];
  sh[t] = s;
  __syncthreads();
  for (int off = 128; off > 0; off >>= 1) {
    if (t < off) sh[t] += sh[t + off];
    __syncthreads();
  }
  if (t == 0) part[b] = sh[0];
}

// single small block: exclusive-scan part[0..nb), write rowptr[n]=E
__global__ __launch_bounds__(1024) void k_scan2(int* __restrict__ part, int nb,
                                                int* __restrict__ rowptr, int n, int E) {
  int t = threadIdx.x;
  __shared__ int sh[1024];
  int v = (t < nb) ? part[t] : 0;
  sh[t] = v;
  __syncthreads();
  for (int off = 1; off < 1024; off <<= 1) {
    int x = (t >= off) ? sh[t - off] : 0;
    __syncthreads();
    sh[t] += x;
    __syncthreads();
  }
  if (t < nb) part[t] = sh[t] - v;  // exclusive
  if (t == 0) rowptr[n] = E;
}

__global__ __launch_bounds__(256) void k_scan3(const int* __restrict__ cnt,
                                               const int* __restrict__ part,
                                               int* __restrict__ rowptr,
                                               int* __restrict__ cursor, int n) {
  int b = blockIdx.x, t = threadIdx.x;
  int base = b * 1024 + t * 4;
  int v[4];
  int s = 0;
#pragma unroll
  for (int i = 0; i < 4; ++i) {
    int idx = base + i;
    v[i] = (idx < n) ? cnt[idx] : 0;
    s += v[i];
  }
  __shared__ int sh[256];
  sh[t] = s;
  __syncthreads();
  for (int off = 1; off < 256; off <<= 1) {
    int x = (t >= off) ? sh[t - off] : 0;
    __syncthreads();
    sh[t] += x;
    __syncthreads();
  }
  int run = part[b] + sh[t] - s;  // exclusive offset for this thread
#pragma unroll
  for (int i = 0; i < 4; ++i) {
    int idx = base + i;
    if (idx < n) { rowptr[idx] = run; cursor[idx] = run; }
    run += v[i];
  }
}

__global__ void k_fill(const void* eidx, const int* flag,
                       const float* __restrict__ dinv, int* cursor,
                       int* __restrict__ csr_src, float* __restrict__ csr_nrm, int E) {
  int e = blockIdx.x * blockDim.x + threadIdx.x;
  if (e >= E) return;
  int is64 = *flag;
  int s = eidx_at(eidx, e, is64);
  int d = eidx_at(eidx, (long long)E + e, is64);
  int pos = atomicAdd(&cursor[d], 1);
  csr_src[pos] = s;
  csr_nrm[pos] = dinv[s] * dinv[d];
}

// X [n,64] @ W [64,COUT] -> T [n,COUT]. One thread per row, W in LDS.
template <int COUT>
__global__ __launch_bounds__(256) void k_matmul(const float* __restrict__ X,
                                                const float* __restrict__ W,
                                                float* __restrict__ T, int n) {
  __shared__ float Ws[64 * COUT];
  for (int i = threadIdx.x; i < 64 * COUT; i += blockDim.x) Ws[i] = W[i];
  __syncthreads();
  int r = blockIdx.x * blockDim.x + threadIdx.x;
  if (r >= n) return;
  float acc[COUT];
#pragma unroll
  for (int j = 0; j < COUT; ++j) acc[j] = 0.f;
  const float4* xr = (const float4*)(X + (size_t)r * 64);
#pragma unroll
  for (int k4 = 0; k4 < 16; ++k4) {
    float4 xv = xr[k4];
    const float xs[4] = {xv.x, xv.y, xv.z, xv.w};
#pragma unroll
    for (int c = 0; c < 4; ++c) {
      int k = k4 * 4 + c;
#pragma unroll
      for (int j = 0; j < COUT; ++j) acc[j] += xs[c] * Ws[k * COUT + j];
    }
  }
  float4* tr = (float4*)(T + (size_t)r * COUT);
#pragma unroll
  for (int j4 = 0; j4 < COUT / 4; ++j4)
    tr[j4] = make_float4(acc[4 * j4], acc[4 * j4 + 1], acc[4 * j4 + 2], acc[4 * j4 + 3]);
}

// One wave per dst row: gather+accumulate incoming edges, fuse self-loop,
// bias, relu. lane < COUT lanes carry one output float each.
template <int COUT, bool RELU>
__global__ __launch_bounds__(256) void k_gather(const float* __restrict__ T,
                                                const int* __restrict__ rowptr,
                                                const int* __restrict__ csr_src,
                                                const float* __restrict__ csr_nrm,
                                                const float* __restrict__ dinv,
                                                const float* __restrict__ b,
                                                float* __restrict__ out, int n) {
  int wave = blockIdx.x * (blockDim.x >> 6) + (threadIdx.x >> 6);
  int lane = threadIdx.x & 63;
  int row = __builtin_amdgcn_readfirstlane(wave);
  if (row >= n) return;
  int beg = rowptr[row];
  int end = rowptr[row + 1];
  float dr = dinv[row];
  float acc = 0.f;
  for (int j = beg; j < end; ++j) {
    int s = csr_src[j];        // scalar load (j uniform)
    float nrm = csr_nrm[j];    // scalar load, independent of s
    if (lane < COUT) acc = fmaf(nrm, T[(size_t)s * COUT + lane], acc);
  }
  if (lane < COUT) {
    float v = acc + dr * dr * T[(size_t)row * COUT + lane] + b[lane];
    if (RELU) v = fmaxf(v, 0.f);
    out[(size_t)row * COUT + lane] = v;
  }
}

extern "C" void kernel_launch(void* const* d_in, const int* in_sizes, int n_in,
                              void* d_out, int out_size, void* d_ws, size_t ws_size,
                              hipStream_t stream) {
  const float* x  = (const float*)d_in[0];
  const void*  ei = d_in[1];
  const float* W1 = (const float*)d_in[2];
  const float* b1 = (const float*)d_in[3];
  const float* W2 = (const float*)d_in[4];
  const float* b2 = (const float*)d_in[5];
  const float* W3 = (const float*)d_in[6];
  const float* b3 = (const float*)d_in[7];
  float* out = (float*)d_out;

  const int n = in_sizes[0] / 64;   // 100000
  const int E = in_sizes[1] / 2;    // 1000000

  char* ws = (char*)d_ws;
  size_t off = 0;
  auto carve = [&](size_t bytes) -> void* {
    void* p = ws + off;
    off = (off + bytes + 255) & ~(size_t)255;
    return p;
  };
  int*   flag    = (int*)carve(16);
  int*   cnt     = (int*)carve(sizeof(int) * n);
  float* dinv    = (float*)carve(sizeof(float) * n);
  int*   rowptr  = (int*)carve(sizeof(int) * (n + 1));
  int*   cursor  = (int*)carve(sizeof(int) * n);
  int*   part    = (int*)carve(sizeof(int) * 1024);
  int*   csr_src = (int*)carve(sizeof(int) * E);
  float* csr_nrm = (float*)carve(sizeof(float) * E);
  float* T       = (float*)carve(sizeof(float) * (size_t)n * 64);
  float* A       = (float*)carve(sizeof(float) * (size_t)n * 64);

  const int B = 256;
  const int gN = (n + B - 1) / B;
  const int gE = (E + B - 1) / B;
  const int gW = (n + 3) / 4;            // 4 waves/block, 1 wave/row
  const int nb = (n + 1023) / 1024;      // scan blocks (98)

  // ---- graph preprocessing (once per call, shared by all 3 layers) ----
  k_flag<<<1, 1, 0, stream>>>(ei, flag);
  hipMemsetAsync(cnt, 0, sizeof(int) * n, stream);
  k_count<<<gE, B, 0, stream>>>(ei, flag, cnt, E);
  k_dinv<<<gN, B, 0, stream>>>(cnt, dinv, n);
  k_scan1<<<nb, B, 0, stream>>>(cnt, part, n);
  k_scan2<<<1, 1024, 0, stream>>>(part, nb, rowptr, n, E);
  k_scan3<<<nb, B, 0, stream>>>(cnt, part, rowptr, cursor, n);
  k_fill<<<gE, B, 0, stream>>>(ei, flag, dinv, cursor, csr_src, csr_nrm, E);

  // ---- layer 1: x -> A ----
  k_matmul<64><<<gN, B, 0, stream>>>(x, W1, T, n);
  k_gather<64, true><<<gW, B, 0, stream>>>(T, rowptr, csr_src, csr_nrm, dinv, b1, A, n);

  // ---- layer 2: A -> A ----
  k_matmul<64><<<gN, B, 0, stream>>>(A, W2, T, n);
  k_gather<64, true><<<gW, B, 0, stream>>>(T, rowptr, csr_src, csr_nrm, dinv, b2, A, n);

  // ---- layer 3: A -> out ----
  k_matmul<32><<<gN, B, 0, stream>>>(A, W3, T, n);
  k_gather<32, false><<<gW, B, 0, stream>>>(T, rowptr, csr_src, csr_nrm, dinv, b3, out, n);
}

// Round 4
// 328.099 us; speedup vs baseline: 6.9687x; 1.2562x over previous
//
#include <hip/hip_runtime.h>
#include <cstdint>
#include <cstddef>

// ---------------------------------------------------------------------------
// GCN 3-layer forward, CSR-gather formulation (no f32 atomics):
//   build CSR by dst once per call; per layer: T = X@W, then per dst row
//   acc[lane] = sum_j nrm[j]*T[src[j]][lane]  + dinv^2*T[row][lane] + b[lane]
//   (self-loop + bias + relu fused into the gather epilogue).
// Round 3: gather edge loop batched 8/4/1 to break the load dependency chain
// (was latency-bound: 14% HBM, 7.5% VALU); k_flag parallelized to one wave.
// ---------------------------------------------------------------------------

__device__ __forceinline__ int eidx_at(const void* p, long long i, int is64) {
  if (is64) return (int)((const long long*)p)[i];
  return ((const int*)p)[i];
}

__global__ void k_flag(const void* eidx, int* flag) {
  // int64 node indices are all < 1e5; int32 data read as u64 has a random
  // index in the high word -> huge values. One wave checks 256 words.
  const unsigned long long* p = (const unsigned long long*)eidx;
  int lane = threadIdx.x & 63;
  int bad = 0;
#pragma unroll
  for (int i = 0; i < 4; ++i) bad |= (p[lane + 64 * i] > 1000000000ULL) ? 1 : 0;
  int any_bad = __any(bad);
  if (lane == 0) *flag = any_bad ? 0 : 1;
}

// histogram of dst (real edges only; self-loop handled in dinv/epilogue)
__global__ void k_count(const void* eidx, const int* flag, int* cnt, int E) {
  int e = blockIdx.x * blockDim.x + threadIdx.x;
  if (e >= E) return;
  int is64 = *flag;
  int d = eidx_at(eidx, (long long)E + e, is64);
  atomicAdd(&cnt[d], 1);
}

__global__ void k_dinv(const int* __restrict__ cnt, float* __restrict__ dinv, int n) {
  int i = blockIdx.x * blockDim.x + threadIdx.x;
  if (i < n) dinv[i] = rsqrtf((float)(cnt[i] + 1));  // +1 self-loop
}

// ---- 3-phase scan: 1024 elems per block (256 thr x 4) ----
__global__ __launch_bounds__(256) void k_scan1(const int* __restrict__ cnt,
                                               int* __restrict__ part, int n) {
  int b = blockIdx.x, t = threadIdx.x;
  int base = b * 1024 + t * 4;
  int s = 0;
#pragma unroll
  for (int i = 0; i < 4; ++i) { int idx = base + i; if (idx < n) s += cnt[idx]; }
  __shared__ int sh[256];
  sh[t] = s;
  __syncthreads();
  for (int off = 128; off > 0; off >>= 1) {
    if (t < off) sh[t] += sh[t + off];
    __syncthreads();
  }
  if (t == 0) part[b] = sh[0];
}

// single small block: exclusive-scan part[0..nb), write rowptr[n]=E
__global__ __launch_bounds__(1024) void k_scan2(int* __restrict__ part, int nb,
                                                int* __restrict__ rowptr, int n, int E) {
  int t = threadIdx.x;
  __shared__ int sh[1024];
  int v = (t < nb) ? part[t] : 0;
  sh[t] = v;
  __syncthreads();
  for (int off = 1; off < 1024; off <<= 1) {
    int x = (t >= off) ? sh[t - off] : 0;
    __syncthreads();
    sh[t] += x;
    __syncthreads();
  }
  if (t < nb) part[t] = sh[t] - v;  // exclusive
  if (t == 0) rowptr[n] = E;
}

__global__ __launch_bounds__(256) void k_scan3(const int* __restrict__ cnt,
                                               const int* __restrict__ part,
                                               int* __restrict__ rowptr,
                                               int* __restrict__ cursor, int n) {
  int b = blockIdx.x, t = threadIdx.x;
  int base = b * 1024 + t * 4;
  int v[4];
  int s = 0;
#pragma unroll
  for (int i = 0; i < 4; ++i) {
    int idx = base + i;
    v[i] = (idx < n) ? cnt[idx] : 0;
    s += v[i];
  }
  __shared__ int sh[256];
  sh[t] = s;
  __syncthreads();
  for (int off = 1; off < 256; off <<= 1) {
    int x = (t >= off) ? sh[t - off] : 0;
    __syncthreads();
    sh[t] += x;
    __syncthreads();
  }
  int run = part[b] + sh[t] - s;  // exclusive offset for this thread
#pragma unroll
  for (int i = 0; i < 4; ++i) {
    int idx = base + i;
    if (idx < n) { rowptr[idx] = run; cursor[idx] = run; }
    run += v[i];
  }
}

__global__ void k_fill(const void* eidx, const int* flag,
                       const float* __restrict__ dinv, int* cursor,
                       int* __restrict__ csr_src, float* __restrict__ csr_nrm, int E) {
  int e = blockIdx.x * blockDim.x + threadIdx.x;
  if (e >= E) return;
  int is64 = *flag;
  int s = eidx_at(eidx, e, is64);
  int d = eidx_at(eidx, (long long)E + e, is64);
  int pos = atomicAdd(&cursor[d], 1);
  csr_src[pos] = s;
  csr_nrm[pos] = dinv[s] * dinv[d];
}

// X [n,64] @ W [64,COUT] -> T [n,COUT]. One thread per row, W in LDS.
template <int COUT>
__global__ __launch_bounds__(256) void k_matmul(const float* __restrict__ X,
                                                const float* __restrict__ W,
                                                float* __restrict__ T, int n) {
  __shared__ float Ws[64 * COUT];
  for (int i = threadIdx.x; i < 64 * COUT; i += blockDim.x) Ws[i] = W[i];
  __syncthreads();
  int r = blockIdx.x * blockDim.x + threadIdx.x;
  if (r >= n) return;
  float acc[COUT];
#pragma unroll
  for (int j = 0; j < COUT; ++j) acc[j] = 0.f;
  const float4* xr = (const float4*)(X + (size_t)r * 64);
#pragma unroll
  for (int k4 = 0; k4 < 16; ++k4) {
    float4 xv = xr[k4];
    const float xs[4] = {xv.x, xv.y, xv.z, xv.w};
#pragma unroll
    for (int c = 0; c < 4; ++c) {
      int k = k4 * 4 + c;
#pragma unroll
      for (int j = 0; j < COUT; ++j) acc[j] += xs[c] * Ws[k * COUT + j];
    }
  }
  float4* tr = (float4*)(T + (size_t)r * COUT);
#pragma unroll
  for (int j4 = 0; j4 < COUT / 4; ++j4)
    tr[j4] = make_float4(acc[4 * j4], acc[4 * j4 + 1], acc[4 * j4 + 2], acc[4 * j4 + 3]);
}

// One wave per dst row. Edge loop batched 8/4/1: all (src,nrm) loads issued,
// then all T-row gathers issued independently -> short dependency chains.
template <int COUT, bool RELU>
__global__ __launch_bounds__(256) void k_gather(const float* __restrict__ T,
                                                const int* __restrict__ rowptr,
                                                const int* __restrict__ csr_src,
                                                const float* __restrict__ csr_nrm,
                                                const float* __restrict__ dinv,
                                                const float* __restrict__ b,
                                                float* __restrict__ out, int n) {
  int wave = blockIdx.x * (blockDim.x >> 6) + (threadIdx.x >> 6);
  int lane = threadIdx.x & 63;
  int row = __builtin_amdgcn_readfirstlane(wave);
  if (row >= n) return;
  int beg = rowptr[row];
  int end = rowptr[row + 1];
  float dr = dinv[row];
  float a0 = 0.f, a1 = 0.f, a2 = 0.f, a3 = 0.f;
  int j = beg;
  if (lane < COUT) {
    for (; j + 8 <= end; j += 8) {
      int s0 = csr_src[j + 0], s1 = csr_src[j + 1], s2 = csr_src[j + 2], s3 = csr_src[j + 3];
      int s4 = csr_src[j + 4], s5 = csr_src[j + 5], s6 = csr_src[j + 6], s7 = csr_src[j + 7];
      float m0 = csr_nrm[j + 0], m1 = csr_nrm[j + 1], m2 = csr_nrm[j + 2], m3 = csr_nrm[j + 3];
      float m4 = csr_nrm[j + 4], m5 = csr_nrm[j + 5], m6 = csr_nrm[j + 6], m7 = csr_nrm[j + 7];
      float t0 = T[(size_t)s0 * COUT + lane];
      float t1 = T[(size_t)s1 * COUT + lane];
      float t2 = T[(size_t)s2 * COUT + lane];
      float t3 = T[(size_t)s3 * COUT + lane];
      float t4 = T[(size_t)s4 * COUT + lane];
      float t5 = T[(size_t)s5 * COUT + lane];
      float t6 = T[(size_t)s6 * COUT + lane];
      float t7 = T[(size_t)s7 * COUT + lane];
      a0 = fmaf(m0, t0, a0); a1 = fmaf(m1, t1, a1);
      a2 = fmaf(m2, t2, a2); a3 = fmaf(m3, t3, a3);
      a0 = fmaf(m4, t4, a0); a1 = fmaf(m5, t5, a1);
      a2 = fmaf(m6, t6, a2); a3 = fmaf(m7, t7, a3);
    }
    if (j + 4 <= end) {
      int s0 = csr_src[j + 0], s1 = csr_src[j + 1], s2 = csr_src[j + 2], s3 = csr_src[j + 3];
      float m0 = csr_nrm[j + 0], m1 = csr_nrm[j + 1], m2 = csr_nrm[j + 2], m3 = csr_nrm[j + 3];
      float t0 = T[(size_t)s0 * COUT + lane];
      float t1 = T[(size_t)s1 * COUT + lane];
      float t2 = T[(size_t)s2 * COUT + lane];
      float t3 = T[(size_t)s3 * COUT + lane];
      a0 = fmaf(m0, t0, a0); a1 = fmaf(m1, t1, a1);
      a2 = fmaf(m2, t2, a2); a3 = fmaf(m3, t3, a3);
      j += 4;
    }
    for (; j < end; ++j) {
      int s = csr_src[j];
      float m = csr_nrm[j];
      a0 = fmaf(m, T[(size_t)s * COUT + lane], a0);
    }
    float acc = (a0 + a1) + (a2 + a3);
    float v = acc + dr * dr * T[(size_t)row * COUT + lane] + b[lane];
    if (RELU) v = fmaxf(v, 0.f);
    out[(size_t)row * COUT + lane] = v;
  }
}

extern "C" void kernel_launch(void* const* d_in, const int* in_sizes, int n_in,
                              void* d_out, int out_size, void* d_ws, size_t ws_size,
                              hipStream_t stream) {
  const float* x  = (const float*)d_in[0];
  const void*  ei = d_in[1];
  const float* W1 = (const float*)d_in[2];
  const float* b1 = (const float*)d_in[3];
  const float* W2 = (const float*)d_in[4];
  const float* b2 = (const float*)d_in[5];
  const float* W3 = (const float*)d_in[6];
  const float* b3 = (const float*)d_in[7];
  float* out = (float*)d_out;

  const int n = in_sizes[0] / 64;   // 100000
  const int E = in_sizes[1] / 2;    // 1000000

  char* ws = (char*)d_ws;
  size_t off = 0;
  auto carve = [&](size_t bytes) -> void* {
    void* p = ws + off;
    off = (off + bytes + 255) & ~(size_t)255;
    return p;
  };
  int*   flag    = (int*)carve(16);
  int*   cnt     = (int*)carve(sizeof(int) * n);
  float* dinv    = (float*)carve(sizeof(float) * n);
  int*   rowptr  = (int*)carve(sizeof(int) * (n + 1));
  int*   cursor  = (int*)carve(sizeof(int) * n);
  int*   part    = (int*)carve(sizeof(int) * 1024);
  int*   csr_src = (int*)carve(sizeof(int) * E);
  float* csr_nrm = (float*)carve(sizeof(float) * E);
  float* T       = (float*)carve(sizeof(float) * (size_t)n * 64);
  float* A       = (float*)carve(sizeof(float) * (size_t)n * 64);

  const int B = 256;
  const int gN = (n + B - 1) / B;
  const int gE = (E + B - 1) / B;
  const int gW = (n + 3) / 4;            // 4 waves/block, 1 wave/row
  const int nb = (n + 1023) / 1024;      // scan blocks (98)

  // ---- graph preprocessing (once per call, shared by all 3 layers) ----
  k_flag<<<1, 64, 0, stream>>>(ei, flag);
  hipMemsetAsync(cnt, 0, sizeof(int) * n, stream);
  k_count<<<gE, B, 0, stream>>>(ei, flag, cnt, E);
  k_dinv<<<gN, B, 0, stream>>>(cnt, dinv, n);
  k_scan1<<<nb, B, 0, stream>>>(cnt, part, n);
  k_scan2<<<1, 1024, 0, stream>>>(part, nb, rowptr, n, E);
  k_scan3<<<nb, B, 0, stream>>>(cnt, part, rowptr, cursor, n);
  k_fill<<<gE, B, 0, stream>>>(ei, flag, dinv, cursor, csr_src, csr_nrm, E);

  // ---- layer 1: x -> A ----
  k_matmul<64><<<gN, B, 0, stream>>>(x, W1, T, n);
  k_gather<64, true><<<gW, B, 0, stream>>>(T, rowptr, csr_src, csr_nrm, dinv, b1, A, n);

  // ---- layer 2: A -> A ----
  k_matmul<64><<<gN, B, 0, stream>>>(A, W2, T, n);
  k_gather<64, true><<<gW, B, 0, stream>>>(T, rowptr, csr_src, csr_nrm, dinv, b2, A, n);

  // ---- layer 3: A -> out ----
  k_matmul<32><<<gN, B, 0, stream>>>(A, W3, T, n);
  k_gather<32, false><<<gW, B, 0, stream>>>(T, rowptr, csr_src, csr_nrm, dinv, b3, out, n);
}